// Round 5
// baseline (491.211 us; speedup 1.0000x reference)
//
#include <hip/hip_runtime.h>
#include <hip/hip_bf16.h>
#include <stdint.h>

typedef __hip_bfloat16 bf16;
typedef __attribute__((ext_vector_type(8))) short bf16x8;
typedef __attribute__((ext_vector_type(4))) float f32x4;

#define MFMA16(a,b,c) __builtin_amdgcn_mfma_f32_16x16x32_bf16((a),(b),(c),0,0,0)

#define BATCH 2
#define S_LEN 2048
#define HID_D 2048
#define NHEAD 16
#define QLR_D 1536
#define KVLR_D 512
#define DN_D 128
#define DR_D 64
#define DV_D 128
#define QKD 192            // DN + DR
// 1/sqrt(192)
#define ATT_SCALE 0.07216878364870322f

__device__ __forceinline__ void async_load16(const bf16* g, bf16* l) {
    __builtin_amdgcn_global_load_lds((const __attribute__((address_space(1))) uint32_t*)g,
                                     (__attribute__((address_space(3))) uint32_t*)l,
                                     16, 0, 0);
}

__device__ __forceinline__ unsigned short f2bf_bits(float f) {
    bf16 h = __float2bfloat16(f);
    return *reinterpret_cast<unsigned short*>(&h);
}

// ---- DPP 16-lane row reductions (VALU pipe, not LDS pipe like __shfl_xor) ----
template <int CTRL>
__device__ __forceinline__ float dpp_mov(float x) {
    return __builtin_bit_cast(float,
        __builtin_amdgcn_update_dpp(0, __builtin_bit_cast(int, x), CTRL, 0xF, 0xF, true));
}
__device__ __forceinline__ float row_max16(float x) {
    x = fmaxf(x, dpp_mov<0xB1>(x));   // quad_perm [1,0,3,2]  (xor 1)
    x = fmaxf(x, dpp_mov<0x4E>(x));   // quad_perm [2,3,0,1]  (xor 2)
    x = fmaxf(x, dpp_mov<0x124>(x));  // row_ror:4
    x = fmaxf(x, dpp_mov<0x128>(x));  // row_ror:8
    return x;
}
__device__ __forceinline__ float row_sum16(float x) {
    x += dpp_mov<0xB1>(x);
    x += dpp_mov<0x4E>(x);
    x += dpp_mov<0x124>(x);
    x += dpp_mov<0x128>(x);
    return x;
}

// ---------------- elementwise fp32 -> bf16 convert ----------------
__global__ void convert_bf16_kernel(const float* __restrict__ in, bf16* __restrict__ out, int n) {
    int idx = blockIdx.x * blockDim.x + threadIdx.x;
    int i4 = idx * 4;
    if (i4 >= n) return;
    float4 v = *(const float4*)(in + i4);
    ushort4 o;
    o.x = f2bf_bits(v.x);
    o.y = f2bf_bits(v.y);
    o.z = f2bf_bits(v.z);
    o.w = f2bf_bits(v.w);
    *(ushort4*)(out + i4) = o;
}

// ---------------- transpose + convert: in (K x N) fp32 -> out (N x K) bf16 ----------------
__global__ void transpose_convert_kernel(const float* __restrict__ in, bf16* __restrict__ out,
                                         int K, int N) {
    __shared__ float tile[32][33];
    int tx = threadIdx.x;   // 0..31
    int ty = threadIdx.y;   // 0..7
    int n0 = blockIdx.x * 32, k0 = blockIdx.y * 32;
#pragma unroll
    for (int i = 0; i < 4; i++)
        tile[ty + i * 8][tx] = in[(size_t)(k0 + ty + i * 8) * N + n0 + tx];
    __syncthreads();
#pragma unroll
    for (int i = 0; i < 4; i++)
        out[(size_t)(n0 + ty + i * 8) * K + k0 + tx] = __float2bfloat16(tile[tx][ty + i * 8]);
}

// ---------------- GEMM: C(MxN) = A(MxK,row,ld=lda) * Bt(NxK,row)^T ----------------
// MODE 0: bf16 row-major (ld=N).
// MODE 1: fp32 row-major (ld=N).
// MODE 2: fused Q up-proj: col<2048 -> q_full nope slot; col>=2048 -> rope slot.
// MODE 4: fused KV up-proj: col<2048 -> k_full nope; <3072 -> k_full rope;
//         >=3072 -> vT transposed (C2[(col-3072)*M + row], packed 4-row store).
template <int MODE>
__global__ __launch_bounds__(256, 2)
void gemm_bt_kernel(const bf16* __restrict__ A, const bf16* __restrict__ Bt,
                    void* __restrict__ C, void* __restrict__ C2,
                    int M, int N, int K, int lda) {
    __shared__ __align__(16) bf16 As[128 * 64];
    __shared__ __align__(16) bf16 Bs[128 * 64];
    const int tid = threadIdx.x;
    const int wave = tid >> 6, lane = tid & 63;
    const int quad = lane >> 4, l16 = lane & 15;
    const int wm = (wave >> 1) * 64, wn = (wave & 1) * 64;
    const int m0 = blockIdx.y * 128, n0 = blockIdx.x * 128;

    f32x4 acc[4][4];
#pragma unroll
    for (int i = 0; i < 4; i++)
#pragma unroll
        for (int j = 0; j < 4; j++)
            acc[i][j] = (f32x4){0.f, 0.f, 0.f, 0.f};

    const bf16* ga = A + (size_t)m0 * lda;
    const bf16* gb = Bt + (size_t)n0 * K;

    for (int k0 = 0; k0 < K; k0 += 64) {
        __syncthreads();
#pragma unroll
        for (int i = 0; i < 4; i++) {
            int chunk = i * 256 + tid;
            int row = chunk >> 3, cseg = chunk & 7;
            int wbase = i * 256 + wave * 64;
            async_load16(ga + (size_t)row * lda + k0 + cseg * 8, &As[wbase * 8]);
            async_load16(gb + (size_t)row * K + k0 + cseg * 8, &Bs[wbase * 8]);
        }
        __syncthreads();
#pragma unroll
        for (int kk = 0; kk < 64; kk += 32) {
            bf16x8 af[4], bfr[4];
#pragma unroll
            for (int t = 0; t < 4; t++) {
                af[t]  = *(const bf16x8*)&As[(wm + t * 16 + l16) * 64 + kk + quad * 8];
                bfr[t] = *(const bf16x8*)&Bs[(wn + t * 16 + l16) * 64 + kk + quad * 8];
            }
#pragma unroll
            for (int tm = 0; tm < 4; tm++)
#pragma unroll
                for (int tn = 0; tn < 4; tn++)
                    acc[tm][tn] = MFMA16(af[tm], bfr[tn], acc[tm][tn]);
        }
    }
    // epilogue: C/D layout col=lane&15, row=quad*4+reg
#pragma unroll
    for (int tm = 0; tm < 4; tm++)
#pragma unroll
        for (int tn = 0; tn < 4; tn++) {
            const int col = n0 + wn + tn * 16 + l16;
            const int row0 = m0 + wm + tm * 16 + quad * 4;
            if constexpr (MODE == 4) {
                if (n0 >= 3072) {   // vT: packed transposed store
                    ushort4 pk;
                    pk.x = f2bf_bits(acc[tm][tn][0]);
                    pk.y = f2bf_bits(acc[tm][tn][1]);
                    pk.z = f2bf_bits(acc[tm][tn][2]);
                    pk.w = f2bf_bits(acc[tm][tn][3]);
                    *(ushort4*)((bf16*)C2 + (size_t)(col - 3072) * M + row0) = pk;
                    continue;
                }
            }
#pragma unroll
            for (int r = 0; r < 4; r++) {
                const int row = row0 + r;
                const float v = acc[tm][tn][r];
                if constexpr (MODE == 0)
                    ((bf16*)C)[(size_t)row * N + col] = __float2bfloat16(v);
                else if constexpr (MODE == 1)
                    ((float*)C)[(size_t)row * N + col] = v;
                else if constexpr (MODE == 2) {
                    if (n0 < 2048) {
                        int hh = col >> 7, dd = col & 127;
                        ((bf16*)C)[(size_t)row * (NHEAD * QKD) + hh * QKD + dd] =
                            __float2bfloat16(v);
                    } else {
                        int c2 = col - 2048, hh = c2 >> 6, dd = c2 & 63;
                        ((bf16*)C)[(size_t)row * (NHEAD * QKD) + hh * QKD + 128 + dd] =
                            __float2bfloat16(v);
                    }
                } else {  // MODE 4, k_full part
                    if (n0 < 2048) {
                        int hh = col >> 7, dd = col & 127;
                        ((bf16*)C)[(size_t)row * (NHEAD * QKD) + hh * QKD + dd] =
                            __float2bfloat16(v);
                    } else {
                        int c2 = col - 2048, hh = c2 >> 6, dd = c2 & 63;
                        ((bf16*)C)[(size_t)row * (NHEAD * QKD) + hh * QKD + 128 + dd] =
                            __float2bfloat16(v);
                    }
                }
            }
        }
}

// ---------------- RoPE in-place on fused (M, NH, 192) buffer, cols 128..191 ----------------
__global__ void rope_kernel(bf16* __restrict__ buf, int nrows) {
    int idx = blockIdx.x * blockDim.x + threadIdx.x;
    if (idx >= nrows * NHEAD * 32) return;
    int j = idx & 31;
    int h = (idx >> 5) & (NHEAD - 1);
    int row = idx >> 9;          // / (16*32)
    int pos = row & (S_LEN - 1); // row = b*S + s
    float inv = __expf(-(float)j * (9.210340371976184f / 32.f));  // ln(10000)/32
    float f = (float)pos * inv;
    float c = __cosf(f), s = __sinf(f);
    bf16* p = buf + (size_t)row * (NHEAD * QKD) + h * QKD + 128 + j;
    float x1 = __bfloat162float(p[0]);
    float x2 = __bfloat162float(p[32]);
    p[0]  = __float2bfloat16(x1 * c - x2 * s);
    p[32] = __float2bfloat16(x2 * c + x1 * s);
}

// ---------------- flash attention: 512 threads, 8 waves x 16 q-rows sharing one ----------
// 56 KB staging tile -> 2 blocks/CU = 16 waves/CU (2x the 256-thread version).
// Pair-balanced schedule: co-resident blocks g and g+256 (same x, bh +/- 16) get
// complementary causal lengths so each CU's total work is ~constant.
__global__ __launch_bounds__(512, 4)
void attn_kernel(const bf16* __restrict__ qf_g, const bf16* __restrict__ kf_g,
                 const bf16* __restrict__ vT, bf16* __restrict__ o_out) {
    __shared__ __align__(16) bf16 k_s[64 * QKD];     // 24 KB
    __shared__ __align__(16) bf16 vt_s[128 * 64];    // 16 KB  (d, kv)
    __shared__ __align__(16) bf16 p_s[8 * 16 * 64];  // 16 KB  per-wave 16x64, quad-XOR swizzled

    const int tid = threadIdx.x;
    const int wave = tid >> 6, lane = tid & 63;
    const int quad = lane >> 4, l16 = lane & 15;
    const int bh = blockIdx.y;
    // complementary pairing: bh<16 gets (15-x), bh>=16 gets x  -> pair sums to 15
    const int qt = (bh < 16) ? (gridDim.x - 1 - blockIdx.x) : blockIdx.x;
    const int q0 = qt * 128;
    const int b = bh >> 4, h = bh & 15;
    const int tokbase = b * S_LEN;
    const int M = BATCH * S_LEN;

    // Q fragments in registers: 1 row-tile (16 rows) x 6 k-chunks
    const int wq = q0 + wave * 16;
    bf16x8 qfr[6];
    {
        const bf16* qrow = qf_g + (size_t)(tokbase + wq + l16) * (NHEAD * QKD)
                                + h * QKD + quad * 8;
#pragma unroll
        for (int kk = 0; kk < 6; kk++)
            qfr[kk] = *(const bf16x8*)(qrow + kk * 32);
    }

    float m_run[4], l_run[4];
#pragma unroll
    for (int r = 0; r < 4; r++) { m_run[r] = -1e30f; l_run[r] = 0.f; }
    f32x4 oacc[8];
#pragma unroll
    for (int d = 0; d < 8; d++) oacc[d] = (f32x4){0.f, 0.f, 0.f, 0.f};

    const int niter = q0 / 64 + 2;
    for (int it = 0; it < niter; it++) {
        const int kv0 = it * 64;
        __syncthreads();
        // stage K tile: 64 rows x 192 = 1536 16B-chunks, 3 issues x 512 threads
#pragma unroll
        for (int i = 0; i < 3; i++) {
            int c = i * 512 + tid;
            int row = c / 24, seg = c % 24;
            async_load16(kf_g + (size_t)(tokbase + kv0 + row) * (NHEAD * QKD) + h * QKD + seg * 8,
                         &k_s[(i * 512 + wave * 64) * 8]);
        }
        // stage V^T tile: 128 d-rows x 64 kv = 1024 chunks, 2 issues
#pragma unroll
        for (int i = 0; i < 2; i++) {
            int c = i * 512 + tid;
            int d = c >> 3, seg = c & 7;
            async_load16(vT + (size_t)(h * 128 + d) * M + tokbase + kv0 + seg * 8,
                         &vt_s[(i * 512 + wave * 64) * 8]);
        }
        __syncthreads();

        if (kv0 <= wq + 15) {
            // S = Q K^T : 16 x 64
            f32x4 sa[4];
#pragma unroll
            for (int nt = 0; nt < 4; nt++) sa[nt] = (f32x4){0.f, 0.f, 0.f, 0.f};
#pragma unroll
            for (int kk = 0; kk < 6; kk++) {
#pragma unroll
                for (int nt = 0; nt < 4; nt++) {
                    bf16x8 bk = *(const bf16x8*)&k_s[(nt * 16 + l16) * QKD + kk * 32 + quad * 8];
                    sa[nt] = MFMA16(qfr[kk], bk, sa[nt]);
                }
            }

            // online softmax + P store — DPP reductions, VALU pipe
            const bool needMask = (kv0 + 63) > wq;
            float alpha[4];
#pragma unroll
            for (int r = 0; r < 4; r++) {
                const int qpos = wq + quad * 4 + r;
                float mx = m_run[r];
                float sv[4];
#pragma unroll
                for (int nt = 0; nt < 4; nt++) {
                    float x = sa[nt][r];
                    if (needMask && (kv0 + nt * 16 + l16 > qpos)) x = -1e30f;
                    sv[nt] = x;
                    mx = fmaxf(mx, x);
                }
                mx = row_max16(mx);
                float rs = 0.f;
#pragma unroll
                for (int nt = 0; nt < 4; nt++) {
                    float p = __expf(ATT_SCALE * (sv[nt] - mx));
                    sv[nt] = p;
                    rs += p;
                }
                rs = row_sum16(rs);
                alpha[r] = __expf(ATT_SCALE * (m_run[r] - mx));
                l_run[r] = alpha[r] * l_run[r] + rs;
                m_run[r] = mx;
                // store P, quad-XOR swizzle on 16-col groups (conflict-free)
                const int row = quad * 4 + r;
#pragma unroll
                for (int nt = 0; nt < 4; nt++)
                    p_s[wave * 1024 + row * 64 + ((nt ^ quad) << 4) + l16] =
                        __float2bfloat16(sv[nt]);
            }
#pragma unroll
            for (int d = 0; d < 8; d++)
#pragma unroll
                for (int r = 0; r < 4; r++) oacc[d][r] *= alpha[r];

            // O += P V : A-frags from swizzled p_s, B-frags from vt_s
#pragma unroll
            for (int kk = 0; kk < 2; kk++) {
                const int grp = (kk * 2 + (quad >> 1)) ^ (l16 >> 2);
                const int lo8 = (quad & 1) * 8;
                bf16x8 ap = *(const bf16x8*)&p_s[wave * 1024 + l16 * 64 + (grp << 4) + lo8];
#pragma unroll
                for (int d = 0; d < 8; d++) {
                    bf16x8 bv = *(const bf16x8*)&vt_s[(d * 16 + l16) * 64 + kk * 32 + quad * 8];
                    oacc[d] = MFMA16(ap, bv, oacc[d]);
                }
            }
        }
    }

    // epilogue: divide by l, write (M, NH*128) bf16
#pragma unroll
    for (int d = 0; d < 8; d++)
#pragma unroll
        for (int r = 0; r < 4; r++) {
            int qrow = wq + quad * 4 + r;
            int col = h * DV_D + d * 16 + l16;
            o_out[(size_t)(tokbase + qrow) * (NHEAD * DV_D) + col] =
                __float2bfloat16(oacc[d][r] / l_run[r]);
        }
}

// ---------------- launch ----------------
extern "C" void kernel_launch(void* const* d_in, const int* in_sizes, int n_in,
                              void* d_out, int out_size, void* d_ws, size_t ws_size,
                              hipStream_t stream) {
    const float* hs        = (const float*)d_in[0];
    const float* w_q_a     = (const float*)d_in[2];
    const float* w_q_nope  = (const float*)d_in[3];
    const float* w_q_rope  = (const float*)d_in[4];
    const float* w_kv_a    = (const float*)d_in[5];
    const float* w_k_nope  = (const float*)d_in[6];
    const float* w_k_rope  = (const float*)d_in[7];
    const float* w_v       = (const float*)d_in[8];
    const float* w_o       = (const float*)d_in[9];
    float* out = (float*)d_out;

    const int M = BATCH * S_LEN;  // 4096

    char* wsp = (char*)d_ws;
    auto alloc = [&](size_t elems) {
        bf16* p = (bf16*)wsp;
        wsp += ((elems * 2 + 255) / 256) * 256;
        return p;
    };
    bf16* hs_b     = alloc((size_t)M * HID_D);
    bf16* w_a_t    = alloc((size_t)2048 * HID_D);          // [q_a(1536) ; kv_a(512)] x 2048
    bf16* wq_up_t  = alloc((size_t)3072 * QLR_D);          // [q_nope(2048) ; q_rope(1024)] x 1536
    bf16* wkv_up_t = alloc((size_t)5120 * KVLR_D);         // [k_nope ; k_rope ; v] x 512
    bf16* wo_t     = alloc((size_t)HID_D * (NHEAD * DV_D));
    bf16* qkv_c    = alloc((size_t)M * 2048);              // [q_c(1536) | kv_c(512)]
    bf16* q_full   = alloc((size_t)M * NHEAD * QKD);
    bf16* k_full   = alloc((size_t)M * NHEAD * QKD);
    bf16* vT       = alloc((size_t)NHEAD * DV_D * M);
    bf16* a_out    = alloc((size_t)M * NHEAD * DV_D);

    // convert hidden states
    {
        int n = M * HID_D;
        convert_bf16_kernel<<<(n / 4 + 255) / 256, 256, 0, stream>>>(hs, hs_b, n);
    }
    // transpose-convert weights into concatenated (N,K) layouts
    dim3 tb(32, 8);
    transpose_convert_kernel<<<dim3(QLR_D / 32, HID_D / 32), tb, 0, stream>>>(w_q_a, w_a_t, HID_D, QLR_D);
    transpose_convert_kernel<<<dim3(KVLR_D / 32, HID_D / 32), tb, 0, stream>>>(w_kv_a, w_a_t + (size_t)QLR_D * HID_D, HID_D, KVLR_D);
    transpose_convert_kernel<<<dim3(2048 / 32, QLR_D / 32), tb, 0, stream>>>(w_q_nope, wq_up_t, QLR_D, 2048);
    transpose_convert_kernel<<<dim3(1024 / 32, QLR_D / 32), tb, 0, stream>>>(w_q_rope, wq_up_t + (size_t)2048 * QLR_D, QLR_D, 1024);
    transpose_convert_kernel<<<dim3(2048 / 32, KVLR_D / 32), tb, 0, stream>>>(w_k_nope, wkv_up_t, KVLR_D, 2048);
    transpose_convert_kernel<<<dim3(1024 / 32, KVLR_D / 32), tb, 0, stream>>>(w_k_rope, wkv_up_t + (size_t)2048 * KVLR_D, KVLR_D, 1024);
    transpose_convert_kernel<<<dim3(2048 / 32, KVLR_D / 32), tb, 0, stream>>>(w_v, wkv_up_t + (size_t)3072 * KVLR_D, KVLR_D, 2048);
    transpose_convert_kernel<<<dim3(HID_D / 32, 2048 / 32), tb, 0, stream>>>(w_o, wo_t, NHEAD * DV_D, HID_D);

    // fused low-rank projection: [q_c | kv_c] = hs @ [w_q_a | w_kv_a]
    gemm_bt_kernel<0><<<dim3(2048 / 128, M / 128), 256, 0, stream>>>(hs_b, w_a_t, qkv_c, nullptr, M, 2048, HID_D, HID_D);
    // fused Q up-projection (nope+rope) into q_full
    gemm_bt_kernel<2><<<dim3(3072 / 128, M / 128), 256, 0, stream>>>(qkv_c, wq_up_t, q_full, nullptr, M, 3072, QLR_D, 2048);
    // fused KV up-projection (k_nope+k_rope+v) into k_full and vT
    gemm_bt_kernel<4><<<dim3(5120 / 128, M / 128), 256, 0, stream>>>(qkv_c + QLR_D, wkv_up_t, k_full, vT, M, 5120, KVLR_D, 2048);

    // rope on fused q/k buffers (cols 128..191 per head)
    {
        int n = M * NHEAD * 32;
        rope_kernel<<<(n + 255) / 256, 256, 0, stream>>>(q_full, M);
        rope_kernel<<<(n + 255) / 256, 256, 0, stream>>>(k_full, M);
    }

    // attention: 512-thread blocks, 8 waves sharing one staging tile
    attn_kernel<<<dim3(S_LEN / 128, BATCH * NHEAD), 512, 0, stream>>>(q_full, k_full, vT, a_out);

    // output projection (fp32 out)
    gemm_bt_kernel<1><<<dim3(HID_D / 128, M / 128), 256, 0, stream>>>(a_out, wo_t, out, nullptr, M, HID_D, NHEAD * DV_D, NHEAD * DV_D);

    (void)in_sizes; (void)n_in; (void)out_size; (void)ws_size;
}

// Round 6
// 443.811 us; speedup vs baseline: 1.1068x; 1.1068x over previous
//
#include <hip/hip_runtime.h>
#include <hip/hip_bf16.h>
#include <stdint.h>

typedef __hip_bfloat16 bf16;
typedef __attribute__((ext_vector_type(8))) short bf16x8;
typedef __attribute__((ext_vector_type(4))) float f32x4;

#define MFMA16(a,b,c) __builtin_amdgcn_mfma_f32_16x16x32_bf16((a),(b),(c),0,0,0)

#define BATCH 2
#define S_LEN 2048
#define HID_D 2048
#define NHEAD 16
#define QLR_D 1536
#define KVLR_D 512
#define DN_D 128
#define DR_D 64
#define DV_D 128
#define QKD 192            // DN + DR
// 1/sqrt(192)
#define ATT_SCALE 0.07216878364870322f

__device__ __forceinline__ void async_load16(const bf16* g, bf16* l) {
    __builtin_amdgcn_global_load_lds((const __attribute__((address_space(1))) uint32_t*)g,
                                     (__attribute__((address_space(3))) uint32_t*)l,
                                     16, 0, 0);
}

__device__ __forceinline__ unsigned short f2bf_bits(float f) {
    bf16 h = __float2bfloat16(f);
    return *reinterpret_cast<unsigned short*>(&h);
}

// ---- DPP 16-lane row reductions (VALU pipe, not LDS pipe like __shfl_xor) ----
template <int CTRL>
__device__ __forceinline__ float dpp_mov(float x) {
    return __builtin_bit_cast(float,
        __builtin_amdgcn_update_dpp(0, __builtin_bit_cast(int, x), CTRL, 0xF, 0xF, true));
}
__device__ __forceinline__ float row_max16(float x) {
    x = fmaxf(x, dpp_mov<0xB1>(x));   // quad_perm [1,0,3,2]  (xor 1)
    x = fmaxf(x, dpp_mov<0x4E>(x));   // quad_perm [2,3,0,1]  (xor 2)
    x = fmaxf(x, dpp_mov<0x124>(x));  // row_ror:4
    x = fmaxf(x, dpp_mov<0x128>(x));  // row_ror:8
    return x;
}
__device__ __forceinline__ float row_sum16(float x) {
    x += dpp_mov<0xB1>(x);
    x += dpp_mov<0x4E>(x);
    x += dpp_mov<0x124>(x);
    x += dpp_mov<0x128>(x);
    return x;
}

// ---------------- elementwise fp32 -> bf16 convert ----------------
__global__ void convert_bf16_kernel(const float* __restrict__ in, bf16* __restrict__ out, int n) {
    int idx = blockIdx.x * blockDim.x + threadIdx.x;
    int i4 = idx * 4;
    if (i4 >= n) return;
    float4 v = *(const float4*)(in + i4);
    ushort4 o;
    o.x = f2bf_bits(v.x);
    o.y = f2bf_bits(v.y);
    o.z = f2bf_bits(v.z);
    o.w = f2bf_bits(v.w);
    *(ushort4*)(out + i4) = o;
}

// ---------------- transpose + convert: in (K x N) fp32 -> out (N x K) bf16 ----------------
__global__ void transpose_convert_kernel(const float* __restrict__ in, bf16* __restrict__ out,
                                         int K, int N) {
    __shared__ float tile[32][33];
    int tx = threadIdx.x;   // 0..31
    int ty = threadIdx.y;   // 0..7
    int n0 = blockIdx.x * 32, k0 = blockIdx.y * 32;
#pragma unroll
    for (int i = 0; i < 4; i++)
        tile[ty + i * 8][tx] = in[(size_t)(k0 + ty + i * 8) * N + n0 + tx];
    __syncthreads();
#pragma unroll
    for (int i = 0; i < 4; i++)
        out[(size_t)(n0 + ty + i * 8) * K + k0 + tx] = __float2bfloat16(tile[tx][ty + i * 8]);
}

// ---------------- GEMM: C(MxN) = A(MxK,row,ld=lda) * Bt(NxK,row)^T ----------------
// LDS tiles use an XOR chunk swizzle: physical 16B-chunk pc holds logical chunk
// pc^(row&7); readers use pc = s ^ (l16&7) -> conflict-free (2 lanes/bank).
// MODE 0: bf16 row-major (ld=N).  MODE 1: fp32 row-major.
// MODE 2: fused Q up-proj: col<2048 -> q_full nope slot; col>=2048 -> rope slot.
// MODE 4: fused KV up-proj: col<2048 -> k_full nope; <3072 -> k_full rope;
//         >=3072 -> vT transposed (C2[(col-3072)*M + row], packed 4-row store).
template <int MODE>
__global__ __launch_bounds__(256, 2)
void gemm_bt_kernel(const bf16* __restrict__ A, const bf16* __restrict__ Bt,
                    void* __restrict__ C, void* __restrict__ C2,
                    int M, int N, int K, int lda) {
    __shared__ __align__(16) bf16 As[128 * 64];
    __shared__ __align__(16) bf16 Bs[128 * 64];
    const int tid = threadIdx.x;
    const int wave = tid >> 6, lane = tid & 63;
    const int quad = lane >> 4, l16 = lane & 15;
    const int wm = (wave >> 1) * 64, wn = (wave & 1) * 64;
    const int m0 = blockIdx.y * 128, n0 = blockIdx.x * 128;

    f32x4 acc[4][4];
#pragma unroll
    for (int i = 0; i < 4; i++)
#pragma unroll
        for (int j = 0; j < 4; j++)
            acc[i][j] = (f32x4){0.f, 0.f, 0.f, 0.f};

    const bf16* ga = A + (size_t)m0 * lda;
    const bf16* gb = Bt + (size_t)n0 * K;

    for (int k0 = 0; k0 < K; k0 += 64) {
        __syncthreads();
#pragma unroll
        for (int i = 0; i < 4; i++) {
            int chunk = i * 256 + tid;
            int row = chunk >> 3, cseg = chunk & 7;
            int csl = cseg ^ (row & 7);           // source chunk for swizzled layout
            int wbase = i * 256 + wave * 64;
            async_load16(ga + (size_t)row * lda + k0 + csl * 8, &As[wbase * 8]);
            async_load16(gb + (size_t)row * K + k0 + csl * 8, &Bs[wbase * 8]);
        }
        __syncthreads();
#pragma unroll
        for (int kk = 0; kk < 64; kk += 32) {
            bf16x8 af[4], bfr[4];
#pragma unroll
            for (int t = 0; t < 4; t++) {
                const int pc = (((kk >> 3) + quad) ^ (l16 & 7)) * 8;
                af[t]  = *(const bf16x8*)&As[(wm + t * 16 + l16) * 64 + pc];
                bfr[t] = *(const bf16x8*)&Bs[(wn + t * 16 + l16) * 64 + pc];
            }
#pragma unroll
            for (int tm = 0; tm < 4; tm++)
#pragma unroll
                for (int tn = 0; tn < 4; tn++)
                    acc[tm][tn] = MFMA16(af[tm], bfr[tn], acc[tm][tn]);
        }
    }
    // epilogue: C/D layout col=lane&15, row=quad*4+reg
#pragma unroll
    for (int tm = 0; tm < 4; tm++)
#pragma unroll
        for (int tn = 0; tn < 4; tn++) {
            const int col = n0 + wn + tn * 16 + l16;
            const int row0 = m0 + wm + tm * 16 + quad * 4;
            if constexpr (MODE == 4) {
                if (n0 >= 3072) {   // vT: packed transposed store
                    ushort4 pk;
                    pk.x = f2bf_bits(acc[tm][tn][0]);
                    pk.y = f2bf_bits(acc[tm][tn][1]);
                    pk.z = f2bf_bits(acc[tm][tn][2]);
                    pk.w = f2bf_bits(acc[tm][tn][3]);
                    *(ushort4*)((bf16*)C2 + (size_t)(col - 3072) * M + row0) = pk;
                    continue;
                }
            }
#pragma unroll
            for (int r = 0; r < 4; r++) {
                const int row = row0 + r;
                const float v = acc[tm][tn][r];
                if constexpr (MODE == 0)
                    ((bf16*)C)[(size_t)row * N + col] = __float2bfloat16(v);
                else if constexpr (MODE == 1)
                    ((float*)C)[(size_t)row * N + col] = v;
                else if constexpr (MODE == 2) {
                    if (n0 < 2048) {
                        int hh = col >> 7, dd = col & 127;
                        ((bf16*)C)[(size_t)row * (NHEAD * QKD) + hh * QKD + dd] =
                            __float2bfloat16(v);
                    } else {
                        int c2 = col - 2048, hh = c2 >> 6, dd = c2 & 63;
                        ((bf16*)C)[(size_t)row * (NHEAD * QKD) + hh * QKD + 128 + dd] =
                            __float2bfloat16(v);
                    }
                } else {  // MODE 4, k_full part
                    if (n0 < 2048) {
                        int hh = col >> 7, dd = col & 127;
                        ((bf16*)C)[(size_t)row * (NHEAD * QKD) + hh * QKD + dd] =
                            __float2bfloat16(v);
                    } else {
                        int c2 = col - 2048, hh = c2 >> 6, dd = c2 & 63;
                        ((bf16*)C)[(size_t)row * (NHEAD * QKD) + hh * QKD + 128 + dd] =
                            __float2bfloat16(v);
                    }
                }
            }
        }
}

// ---------------- RoPE in-place on fused (M, NH, 192) buffer, cols 128..191 ----------------
__global__ void rope_kernel(bf16* __restrict__ buf, int nrows) {
    int idx = blockIdx.x * blockDim.x + threadIdx.x;
    if (idx >= nrows * NHEAD * 32) return;
    int j = idx & 31;
    int h = (idx >> 5) & (NHEAD - 1);
    int row = idx >> 9;          // / (16*32)
    int pos = row & (S_LEN - 1); // row = b*S + s
    float inv = __expf(-(float)j * (9.210340371976184f / 32.f));  // ln(10000)/32
    float f = (float)pos * inv;
    float c = __cosf(f), s = __sinf(f);
    bf16* p = buf + (size_t)row * (NHEAD * QKD) + h * QKD + 128 + j;
    float x1 = __bfloat162float(p[0]);
    float x2 = __bfloat162float(p[32]);
    p[0]  = __float2bfloat16(x1 * c - x2 * s);
    p[32] = __float2bfloat16(x2 * c + x1 * s);
}

// ---------------- flash attention: 128 q-rows/block, Q in regs, DPP softmax,  -------------
// XOR-swizzled K/V LDS (conflict-free), pair-balanced causal schedule.
__global__ __launch_bounds__(256, 2)
void attn_kernel(const bf16* __restrict__ qf_g, const bf16* __restrict__ kf_g,
                 const bf16* __restrict__ vT, bf16* __restrict__ o_out) {
    __shared__ __align__(16) bf16 k_s[64 * QKD];     // 24 KB, chunk-swizzled
    __shared__ __align__(16) bf16 vt_s[128 * 64];    // 16 KB  (d, kv), chunk-swizzled
    __shared__ __align__(16) bf16 p_s[4 * 32 * 64];  // 16 KB  per-wave 32x64, quad-XOR swizzled

    const int tid = threadIdx.x;
    const int wave = tid >> 6, lane = tid & 63;
    const int quad = lane >> 4, l16 = lane & 15;
    const int bh = blockIdx.y;
    // complementary pairing: bh<16 gets (15-x), bh>=16 gets x  -> pair sums to 15
    const int qt = (bh < 16) ? (gridDim.x - 1 - blockIdx.x) : blockIdx.x;
    const int q0 = qt * 128;
    const int b = bh >> 4, h = bh & 15;
    const int tokbase = b * S_LEN;
    const int M = BATCH * S_LEN;

    // Q fragments in registers: 2 row-tiles x 6 k-chunks
    const int wq = q0 + wave * 32;
    bf16x8 qfr[2][6];
#pragma unroll
    for (int mt = 0; mt < 2; mt++) {
        const bf16* qrow = qf_g + (size_t)(tokbase + wq + mt * 16 + l16) * (NHEAD * QKD)
                                + h * QKD + quad * 8;
#pragma unroll
        for (int kk = 0; kk < 6; kk++)
            qfr[mt][kk] = *(const bf16x8*)(qrow + kk * 32);
    }

    float m_run[2][4], l_run[2][4];
#pragma unroll
    for (int mt = 0; mt < 2; mt++)
#pragma unroll
        for (int r = 0; r < 4; r++) { m_run[mt][r] = -1e30f; l_run[mt][r] = 0.f; }
    f32x4 oacc[2][8];
#pragma unroll
    for (int mt = 0; mt < 2; mt++)
#pragma unroll
        for (int d = 0; d < 8; d++) oacc[mt][d] = (f32x4){0.f, 0.f, 0.f, 0.f};

    const int niter = q0 / 64 + 2;
    for (int it = 0; it < niter; it++) {
        const int kv0 = it * 64;
        __syncthreads();
        // stage K tile: 64 rows x 24 chunks, source chunk XOR-swizzled by row
#pragma unroll
        for (int i = 0; i < 6; i++) {
            int c = i * 256 + tid;
            int row = c / 24, seg = c % 24;
            int sl = (seg & 0x18) | ((seg ^ row) & 7);
            async_load16(kf_g + (size_t)(tokbase + kv0 + row) * (NHEAD * QKD) + h * QKD + sl * 8,
                         &k_s[(i * 256 + wave * 64) * 8]);
        }
        // stage V^T tile: 128 d-rows x 8 chunks, XOR-swizzled by d-row
#pragma unroll
        for (int i = 0; i < 4; i++) {
            int c = i * 256 + tid;
            int d = c >> 3, seg = c & 7;
            int sl = seg ^ (d & 7);
            async_load16(vT + (size_t)(h * 128 + d) * M + tokbase + kv0 + sl * 8,
                         &vt_s[(i * 256 + wave * 64) * 8]);
        }
        __syncthreads();

        if (kv0 <= wq + 31) {
            const bool do0 = kv0 <= wq + 15;  // mt=0 tile not fully masked
            // S = Q K^T : 2 x (16 x 64)
            f32x4 sa[2][4];
#pragma unroll
            for (int mt = 0; mt < 2; mt++)
#pragma unroll
                for (int nt = 0; nt < 4; nt++) sa[mt][nt] = (f32x4){0.f, 0.f, 0.f, 0.f};
#pragma unroll
            for (int kk = 0; kk < 6; kk++) {
                const int lc = kk * 4 + quad;                       // logical chunk 0..23
                const int pc = ((lc & 0x18) | ((lc ^ l16) & 7)) * 8; // physical elem offset
                bf16x8 bk[4];
#pragma unroll
                for (int nt = 0; nt < 4; nt++)
                    bk[nt] = *(const bf16x8*)&k_s[(nt * 16 + l16) * QKD + pc];
#pragma unroll
                for (int mt = 0; mt < 2; mt++)
#pragma unroll
                    for (int nt = 0; nt < 4; nt++)
                        sa[mt][nt] = MFMA16(qfr[mt][kk], bk[nt], sa[mt][nt]);
            }

            // online softmax + P store (per row-tile) — DPP reductions, VALU pipe
            auto softmax_mt = [&](int mt) {
                const int qmin = wq + mt * 16;
                const bool needMask = (kv0 + 63) > qmin;
                float alpha[4];
#pragma unroll
                for (int r = 0; r < 4; r++) {
                    const int qpos = qmin + quad * 4 + r;
                    float mx = m_run[mt][r];
                    float sv[4];
#pragma unroll
                    for (int nt = 0; nt < 4; nt++) {
                        float x = sa[mt][nt][r];
                        if (needMask && (kv0 + nt * 16 + l16 > qpos)) x = -1e30f;
                        sv[nt] = x;
                        mx = fmaxf(mx, x);
                    }
                    mx = row_max16(mx);
                    float rs = 0.f;
#pragma unroll
                    for (int nt = 0; nt < 4; nt++) {
                        float p = __expf(ATT_SCALE * (sv[nt] - mx));
                        sv[nt] = p;
                        rs += p;
                    }
                    rs = row_sum16(rs);
                    alpha[r] = __expf(ATT_SCALE * (m_run[mt][r] - mx));
                    l_run[mt][r] = alpha[r] * l_run[mt][r] + rs;
                    m_run[mt][r] = mx;
                    // store P, quad-XOR swizzle on 16-col groups (conflict-free)
                    const int row = mt * 16 + quad * 4 + r;
#pragma unroll
                    for (int nt = 0; nt < 4; nt++)
                        p_s[wave * 2048 + row * 64 + ((nt ^ quad) << 4) + l16] =
                            __float2bfloat16(sv[nt]);
                }
#pragma unroll
                for (int d = 0; d < 8; d++)
#pragma unroll
                    for (int r = 0; r < 4; r++) oacc[mt][d][r] *= alpha[r];
            };
            if (do0) softmax_mt(0);
            softmax_mt(1);

            // O += P V : A-frags from swizzled p_s, B-frags from swizzled vt_s
#pragma unroll
            for (int kk = 0; kk < 2; kk++) {
                const int pcv = ((kk * 4 + quad) ^ (l16 & 7)) * 8;
                bf16x8 bv[8];
#pragma unroll
                for (int d = 0; d < 8; d++)
                    bv[d] = *(const bf16x8*)&vt_s[(d * 16 + l16) * 64 + pcv];
                const int grp = (kk * 2 + (quad >> 1)) ^ (l16 >> 2);
                const int lo8 = (quad & 1) * 8;
                bf16x8 ap1 = *(const bf16x8*)&p_s[wave * 2048 + (16 + l16) * 64 + (grp << 4) + lo8];
                if (do0) {
                    bf16x8 ap0 = *(const bf16x8*)&p_s[wave * 2048 + l16 * 64 + (grp << 4) + lo8];
#pragma unroll
                    for (int d = 0; d < 8; d++) oacc[0][d] = MFMA16(ap0, bv[d], oacc[0][d]);
                }
#pragma unroll
                for (int d = 0; d < 8; d++) oacc[1][d] = MFMA16(ap1, bv[d], oacc[1][d]);
            }
        }
    }

    // epilogue: divide by l, write (M, NH*128) bf16
#pragma unroll
    for (int mt = 0; mt < 2; mt++)
#pragma unroll
        for (int d = 0; d < 8; d++)
#pragma unroll
            for (int r = 0; r < 4; r++) {
                int qrow = wq + mt * 16 + quad * 4 + r;
                int col = h * DV_D + d * 16 + l16;
                o_out[(size_t)(tokbase + qrow) * (NHEAD * DV_D) + col] =
                    __float2bfloat16(oacc[mt][d][r] / l_run[mt][r]);
            }
}

// ---------------- launch ----------------
extern "C" void kernel_launch(void* const* d_in, const int* in_sizes, int n_in,
                              void* d_out, int out_size, void* d_ws, size_t ws_size,
                              hipStream_t stream) {
    const float* hs        = (const float*)d_in[0];
    const float* w_q_a     = (const float*)d_in[2];
    const float* w_q_nope  = (const float*)d_in[3];
    const float* w_q_rope  = (const float*)d_in[4];
    const float* w_kv_a    = (const float*)d_in[5];
    const float* w_k_nope  = (const float*)d_in[6];
    const float* w_k_rope  = (const float*)d_in[7];
    const float* w_v       = (const float*)d_in[8];
    const float* w_o       = (const float*)d_in[9];
    float* out = (float*)d_out;

    const int M = BATCH * S_LEN;  // 4096

    char* wsp = (char*)d_ws;
    auto alloc = [&](size_t elems) {
        bf16* p = (bf16*)wsp;
        wsp += ((elems * 2 + 255) / 256) * 256;
        return p;
    };
    bf16* hs_b     = alloc((size_t)M * HID_D);
    bf16* w_a_t    = alloc((size_t)2048 * HID_D);          // [q_a(1536) ; kv_a(512)] x 2048
    bf16* wq_up_t  = alloc((size_t)3072 * QLR_D);          // [q_nope(2048) ; q_rope(1024)] x 1536
    bf16* wkv_up_t = alloc((size_t)5120 * KVLR_D);         // [k_nope ; k_rope ; v] x 512
    bf16* wo_t     = alloc((size_t)HID_D * (NHEAD * DV_D));
    bf16* qkv_c    = alloc((size_t)M * 2048);              // [q_c(1536) | kv_c(512)]
    bf16* q_full   = alloc((size_t)M * NHEAD * QKD);
    bf16* k_full   = alloc((size_t)M * NHEAD * QKD);
    bf16* vT       = alloc((size_t)NHEAD * DV_D * M);
    bf16* a_out    = alloc((size_t)M * NHEAD * DV_D);

    // convert hidden states
    {
        int n = M * HID_D;
        convert_bf16_kernel<<<(n / 4 + 255) / 256, 256, 0, stream>>>(hs, hs_b, n);
    }
    // transpose-convert weights into concatenated (N,K) layouts
    dim3 tb(32, 8);
    transpose_convert_kernel<<<dim3(QLR_D / 32, HID_D / 32), tb, 0, stream>>>(w_q_a, w_a_t, HID_D, QLR_D);
    transpose_convert_kernel<<<dim3(KVLR_D / 32, HID_D / 32), tb, 0, stream>>>(w_kv_a, w_a_t + (size_t)QLR_D * HID_D, HID_D, KVLR_D);
    transpose_convert_kernel<<<dim3(2048 / 32, QLR_D / 32), tb, 0, stream>>>(w_q_nope, wq_up_t, QLR_D, 2048);
    transpose_convert_kernel<<<dim3(1024 / 32, QLR_D / 32), tb, 0, stream>>>(w_q_rope, wq_up_t + (size_t)2048 * QLR_D, QLR_D, 1024);
    transpose_convert_kernel<<<dim3(2048 / 32, KVLR_D / 32), tb, 0, stream>>>(w_k_nope, wkv_up_t, KVLR_D, 2048);
    transpose_convert_kernel<<<dim3(1024 / 32, KVLR_D / 32), tb, 0, stream>>>(w_k_rope, wkv_up_t + (size_t)2048 * KVLR_D, KVLR_D, 1024);
    transpose_convert_kernel<<<dim3(2048 / 32, KVLR_D / 32), tb, 0, stream>>>(w_v, wkv_up_t + (size_t)3072 * KVLR_D, KVLR_D, 2048);
    transpose_convert_kernel<<<dim3(HID_D / 32, 2048 / 32), tb, 0, stream>>>(w_o, wo_t, NHEAD * DV_D, HID_D);

    // fused low-rank projection: [q_c | kv_c] = hs @ [w_q_a | w_kv_a]
    gemm_bt_kernel<0><<<dim3(2048 / 128, M / 128), 256, 0, stream>>>(hs_b, w_a_t, qkv_c, nullptr, M, 2048, HID_D, HID_D);
    // fused Q up-projection (nope+rope) into q_full
    gemm_bt_kernel<2><<<dim3(3072 / 128, M / 128), 256, 0, stream>>>(qkv_c, wq_up_t, q_full, nullptr, M, 3072, QLR_D, 2048);
    // fused KV up-projection (k_nope+k_rope+v) into k_full and vT
    gemm_bt_kernel<4><<<dim3(5120 / 128, M / 128), 256, 0, stream>>>(qkv_c + QLR_D, wkv_up_t, k_full, vT, M, 5120, KVLR_D, 2048);

    // rope on fused q/k buffers (cols 128..191 per head)
    {
        int n = M * NHEAD * 32;
        rope_kernel<<<(n + 255) / 256, 256, 0, stream>>>(q_full, M);
        rope_kernel<<<(n + 255) / 256, 256, 0, stream>>>(k_full, M);
    }

    // attention
    attn_kernel<<<dim3(S_LEN / 128, BATCH * NHEAD), 256, 0, stream>>>(q_full, k_full, vT, a_out);

    // output projection (fp32 out)
    gemm_bt_kernel<1><<<dim3(HID_D / 128, M / 128), 256, 0, stream>>>(a_out, wo_t, out, nullptr, M, HID_D, NHEAD * DV_D, NHEAD * DV_D);

    (void)in_sizes; (void)n_in; (void)out_size; (void)ws_size;
}